// Round 12
// baseline (302.658 us; speedup 1.0000x reference)
//
#include <hip/hip_runtime.h>
#include <hip/hip_bf16.h>

// Edges GNN message MLP: per-edge RBF(100) + gather h[src],h[dst] (64+64)
// -> Linear(228->128) -> SiLU -> Linear(128->64).
// R14 = R12 layouts (operand-swapped 32x32x16, zero-shuffle rho/pi packs,
// clean stores, RBF recurrence) + REGISTER-PEAK RESTRUCTURE for 4 waves/SIMD:
// layer 1 runs as TWO PASSES of 2 hidden tiles. Per pass acc[2] (32 regs)
// covers all 15 k-steps then converts to P and dies. All 8 gathers (src+dst)
// issue BEFORE the staging barrier (32 regs, live through both passes) --
// also kills the mid-kernel dst-gather stall. RBF regenerated per pass.
// Peak ~100-110 regs (was ~160 across R11-R13 => 3 waves/SIMD; R13 proved
// the waves_per_eu hint alone cannot restructure liveness). sched_barrier(0)
// pins the pass boundary so the scheduler can't re-merge the passes.
// LDS = 60K (B1) + 16K (B2) = 76 KB -> 2 blocks/CU @ 512 thr, one barrier.

#define FEAT      64
#define NMU       100
#define K1_REAL   228
#define WEDGES    32        // edges per wave (one 32-row m-tile)
#define NWAVES    8
#define BEDGES    (WEDGES * NWAVES)   // 256 edges per block
#define HN8       400000    // (50000*64)/8 bf16x8 groups in h
#define B1N_ELEMS 30720     // 30 (ksh) * 128 (n) * 8 (j) bf16 = 60 KB
#define B2N_ELEMS 8192      // 16 (sh) * 64 (slot) * 8 (j) bf16 = 16 KB
#define RBF_C     0.81873075f   // exp(-0.2)

typedef __bf16  bf16x8 __attribute__((ext_vector_type(8)));
typedef __bf16  bf16x2 __attribute__((ext_vector_type(2)));
typedef float   fx16   __attribute__((ext_vector_type(16)));

// Pack W1 [128 x 228] -> B1[(ksh*128 + n)*8 + j] = W1[n][8*ksh + j]
// (ksh = ks*2 + h5, ks = 0..14; zero for k >= 228). 32x32x16 A-frag order:
// lane l reads row n = tile*32 + (l&31), k = 8*(l>>5) + j contiguous 16B.
// Pack W2 [64 x 128] -> B2[(sh*64 + n2t*32 + r)*8 + j] =
//   W2[n2t*32 + pi(r)][rho(sh,j)]
// rho = k-slot -> H-row perm making layer2's B-fragment lane-local;
// pi(r) = 16*((r>>2)&1) + 4*(r>>3) + (r&3): D-row r holds output feature
// pi(r), so lane (m,h5) owns features n2t*32 + 16*h5 + (0..15) contiguous.
__global__ void pack_w(const float* __restrict__ W1, const float* __restrict__ W2,
                       __bf16* __restrict__ B1, __bf16* __restrict__ B2) {
    int i = blockIdx.x * 256 + threadIdx.x;     // 0..38911
    if (i < B1N_ELEMS) {
        int j   = i & 7;
        int n   = (i >> 3) & 127;
        int ksh = i >> 10;                      // 0..29
        int k   = ksh * 8 + j;                  // 0..239
        float v = (k < K1_REAL) ? W1[n * K1_REAL + k] : 0.0f;
        B1[i] = (__bf16)v;
    } else if (i < B1N_ELEMS + B2N_ELEMS) {
        int t    = i - B1N_ELEMS;
        int j    = t & 7;
        int slot = (t >> 3) & 63;               // n2t*32 + r
        int sh   = t >> 9;                      // 0..15
        int r    = slot & 31;
        int n2t  = slot >> 5;
        int f    = (((r >> 2) & 1) << 4) | ((r >> 3) << 2) | (r & 3);
        int rho  = ((sh >> 2) << 5) | (((sh >> 1) & 1) << 4)
                 | ((j >> 2) << 3) | ((sh & 1) << 2) | (j & 3);
        B2[t] = (__bf16)W2[(n2t * 32 + f) * 128 + rho];
    }
}

// Convert h [50000 x 64] fp32 -> bf16 table (row-major, same layout).
__global__ void pack_h(const float* __restrict__ h, __bf16* __restrict__ hb) {
    int i = blockIdx.x * 256 + threadIdx.x;     // one bf16x8 group each
    if (i >= HN8) return;
    const float4* p = (const float4*)h + (size_t)i * 2;
    float4 v0 = p[0];
    float4 v1 = p[1];
    bf16x8 b = { (__bf16)v0.x, (__bf16)v0.y, (__bf16)v0.z, (__bf16)v0.w,
                 (__bf16)v1.x, (__bf16)v1.y, (__bf16)v1.z, (__bf16)v1.w };
    ((bf16x8*)hb)[i] = b;
}

__device__ __forceinline__ bf16x8 hfrag_f32(const float* __restrict__ h, int node, int cb) {
    const float4* p = (const float4*)(h + (size_t)node * FEAT + cb);
    float4 v0 = p[0];
    float4 v1 = p[1];
    bf16x8 a = { (__bf16)v0.x, (__bf16)v0.y, (__bf16)v0.z, (__bf16)v0.w,
                 (__bf16)v1.x, (__bf16)v1.y, (__bf16)v1.z, (__bf16)v1.w };
    return a;
}

__device__ __forceinline__ float silu(float z) {
    // v_rcp_f32 (~1 ulp) -- error far below bf16 storage rounding.
    return z * __builtin_amdgcn_rcpf(1.0f + __expf(-z));
}

template<bool HB16>
__global__
__attribute__((amdgpu_flat_work_group_size(512, 512), amdgpu_waves_per_eu(4)))
void edges_fused(const float* __restrict__ h,
                 const __bf16* __restrict__ hb,
                 const int*   __restrict__ src,
                 const int*   __restrict__ dst,
                 const float* __restrict__ enorm,
                 const float* __restrict__ mu,
                 const __bf16* __restrict__ B1,
                 const __bf16* __restrict__ B2,
                 float* __restrict__ out,
                 int E) {
    // 60K + 16K = 76 KB static LDS -> 2 blocks/CU.
    __shared__ __align__(16) __bf16 B1s[B1N_ELEMS];
    __shared__ __align__(16) __bf16 B2s[B2N_ELEMS];

    const int tid = threadIdx.x;
    const int w   = tid >> 6;
    const int m   = tid & 31;          // edge within the wave's 32-row tile
    const int h5  = (tid >> 5) & 1;    // lane>>5: k-half selector
    const int g0  = blockIdx.x * BEDGES + w * WEDGES;
    const bool act = (g0 < E);

    // ---- Edge data + ALL gathers (src AND dst) before the staging barrier;
    // latency fully covered by the weight stage + barrier. 32 VGPRs live.
    float dval;
    bf16x8 ags[4];                     // src k-chunks 16*ks + 8*h5 .. +7
    bf16x8 agd[4];                     // dst k-chunks
    if (act) {
        int e = g0 + m;
        int nsrc = src[e];
        int ndst = dst[e];
        dval = enorm[e];
#pragma unroll
        for (int ks = 0; ks < 4; ++ks) {
            const int cb = ks * 16 + h5 * 8;
            if constexpr (HB16) {
                ags[ks] = *(const bf16x8*)(hb + (size_t)nsrc * FEAT + cb);
                agd[ks] = *(const bf16x8*)(hb + (size_t)ndst * FEAT + cb);
            } else {
                ags[ks] = hfrag_f32(h, nsrc, cb);
                agd[ks] = hfrag_f32(h, ndst, cb);
            }
        }
    }

    // ---- Stage weights into LDS (once per block) ----
    {
        const bf16x8* gB1 = (const bf16x8*)B1;
        const bf16x8* gB2 = (const bf16x8*)B2;
        bf16x8* sB1 = (bf16x8*)B1s;
        bf16x8* sB2 = (bf16x8*)B2s;
#pragma unroll
        for (int it = 0; it < 8; ++it) {         // 3840 groups / 512 thr
            int g = it * 512 + tid;
            if (g < B1N_ELEMS / 8) sB1[g] = gB1[g];
        }
#pragma unroll
        for (int it = 0; it < 2; ++it) {         // 1024 groups / 512 thr
            int g = it * 512 + tid;
            sB2[g] = gB2[g];
        }
    }
    __syncthreads();
    if (!act) return;                            // after the only barrier

    // ---- Layer 1 in TWO PASSES over hidden halves (2x 32-row tiles each).
    // Pass p covers hidden tiles nt1 = 2p, 2p+1 with acc[2] (32 regs), runs
    // all 15 k-steps, silu-packs into P, then acc dies. P[nt1*8+gp] is
    // layer2 k-step s=nt1*2+t's B-fragment word (gp = 4t+i).
    uint32_t P[32];

#pragma unroll
    for (int p = 0; p < 2; ++p) {
        fx16 acc[2] = {};
        const int tb0 = (2 * p) * 256;           // B1s bf16-offset of tile 2p
        const int tb1 = (2 * p + 1) * 256;

        // RBF k-steps (regenerated per pass; geometric recurrence, exact on
        // the uniform 0.1 grid; window 0.7 wide cannot span flushed-zero ->
        // significant, so underflow-propagation is harmless).
#pragma unroll
        for (int ks = 8; ks < 14; ++ks) {
            const int c0 = ks * 16 - 128 + h5 * 8;   // RBF col base, < 96
            const float t0 = mu[c0] - dval;
            float v = __expf(-10.f * t0 * t0);
            float rr = __expf(-2.f * t0 - 0.1f);
            float e0 = v, e1, e2, e3, e4, e5, e6, e7;
            v *= rr; rr *= RBF_C; e1 = v;
            v *= rr; rr *= RBF_C; e2 = v;
            v *= rr; rr *= RBF_C; e3 = v;
            v *= rr; rr *= RBF_C; e4 = v;
            v *= rr; rr *= RBF_C; e5 = v;
            v *= rr; rr *= RBF_C; e6 = v;
            v *= rr;              e7 = v;
            bf16x8 a = { (__bf16)e0, (__bf16)e1, (__bf16)e2, (__bf16)e3,
                         (__bf16)e4, (__bf16)e5, (__bf16)e6, (__bf16)e7 };
            const int base = ((ks * 2 + h5) * 128 + m) * 8;
            bf16x8 a0 = *(const bf16x8*)&B1s[base + tb0];
            bf16x8 a1 = *(const bf16x8*)&B1s[base + tb1];
            acc[0] = __builtin_amdgcn_mfma_f32_32x32x16_bf16(a0, a, acc[0], 0, 0, 0);
            acc[1] = __builtin_amdgcn_mfma_f32_32x32x16_bf16(a1, a, acc[1], 0, 0, 0);
        }
        // ks = 14: cols 224..239; real only k < 228 -> h5==0, j<4 (direct).
        {
            float4 m7 = *(const float4*)(mu + 96);
            const float d = dval;
            const bool lo = (h5 == 0);
            const __bf16 zz = (__bf16)0.0f;
            float t0 = m7.x - d, t1 = m7.y - d, t2 = m7.z - d, t3 = m7.w - d;
            bf16x8 a = { lo ? (__bf16)__expf(-10.f * t0 * t0) : zz,
                         lo ? (__bf16)__expf(-10.f * t1 * t1) : zz,
                         lo ? (__bf16)__expf(-10.f * t2 * t2) : zz,
                         lo ? (__bf16)__expf(-10.f * t3 * t3) : zz,
                         zz, zz, zz, zz };
            const int base = ((14 * 2 + h5) * 128 + m) * 8;
            bf16x8 a0 = *(const bf16x8*)&B1s[base + tb0];
            bf16x8 a1 = *(const bf16x8*)&B1s[base + tb1];
            acc[0] = __builtin_amdgcn_mfma_f32_32x32x16_bf16(a0, a, acc[0], 0, 0, 0);
            acc[1] = __builtin_amdgcn_mfma_f32_32x32x16_bf16(a1, a, acc[1], 0, 0, 0);
        }
        // ks = 0..3: src features; ks = 4..7: dst features (all in regs).
#pragma unroll
        for (int ks = 0; ks < 8; ++ks) {
            bf16x8 x = (ks < 4) ? ags[ks] : agd[ks - 4];
            const int base = ((ks * 2 + h5) * 128 + m) * 8;
            bf16x8 a0 = *(const bf16x8*)&B1s[base + tb0];
            bf16x8 a1 = *(const bf16x8*)&B1s[base + tb1];
            acc[0] = __builtin_amdgcn_mfma_f32_32x32x16_bf16(a0, x, acc[0], 0, 0, 0);
            acc[1] = __builtin_amdgcn_mfma_f32_32x32x16_bf16(a1, x, acc[1], 0, 0, 0);
        }

        // SiLU + pack this half into P; acc dies here.
#pragma unroll
        for (int c = 0; c < 2; ++c)
#pragma unroll
            for (int gp = 0; gp < 8; ++gp) {
                union { bf16x2 v; uint32_t u; } cv;
                cv.v = (bf16x2){ (__bf16)silu(acc[c][2 * gp]),
                                 (__bf16)silu(acc[c][2 * gp + 1]) };
                P[(2 * p + c) * 8 + gp] = cv.u;
            }

        // Pin the pass boundary: no cross-pass scheduling (would re-merge
        // the passes and recreate the 160-reg peak R11-R13 suffered).
        __builtin_amdgcn_sched_barrier(0);
    }

    // ---- Layer 2: O^T[64 x 32] = W2[64 x 128] . H^T[128 x 32] ----
    fx16 acc2[2] = {};
#pragma unroll
    for (int s = 0; s < 8; ++s) {
        union { uint32_t u[4]; bf16x8 v; } uu;
        uu.u[0] = P[4 * s + 0]; uu.u[1] = P[4 * s + 1];
        uu.u[2] = P[4 * s + 2]; uu.u[3] = P[4 * s + 3];
        const int base2 = ((s * 2 + h5) * 64 + m) * 8;
#pragma unroll
        for (int n2t = 0; n2t < 2; ++n2t) {
            bf16x8 a2 = *(const bf16x8*)&B2s[base2 + n2t * 256];
            acc2[n2t] = __builtin_amdgcn_mfma_f32_32x32x16_bf16(a2, uu.v, acc2[n2t], 0, 0, 0);
        }
    }

    // ---- Store: pi made lane features contiguous: lane (m,h5) owns output
    // features n2t*32 + h5*16 + reg (reg 0..15) -> 2x 64B contiguous runs.
    float* orow = out + (size_t)(g0 + m) * 64 + h5 * 16;
#pragma unroll
    for (int n2t = 0; n2t < 2; ++n2t)
#pragma unroll
        for (int qd = 0; qd < 4; ++qd) {
            float4 st = { acc2[n2t][4 * qd + 0], acc2[n2t][4 * qd + 1],
                          acc2[n2t][4 * qd + 2], acc2[n2t][4 * qd + 3] };
            *(float4*)(orow + n2t * 32 + qd * 4) = st;
        }
}

extern "C" void kernel_launch(void* const* d_in, const int* in_sizes, int n_in,
                              void* d_out, int out_size, void* d_ws, size_t ws_size,
                              hipStream_t stream) {
    const float* h   = (const float*)d_in[0];
    const int*   src = (const int*)d_in[1];
    const int*   dst = (const int*)d_in[2];
    const float* en  = (const float*)d_in[3];
    const float* mu  = (const float*)d_in[4];
    const float* W1  = (const float*)d_in[5];
    const float* W2  = (const float*)d_in[6];

    __bf16* B1 = (__bf16*)d_ws;                            // 61440 B
    __bf16* B2 = (__bf16*)((char*)d_ws + 61440);           // 16384 B
    __bf16* HB = (__bf16*)((char*)d_ws + 77824);           // 6.4 MB

    const size_t ws_needed = 77824 + (size_t)HN8 * 8 * sizeof(__bf16);
    const bool   use_hb    = ws_size >= ws_needed;

    pack_w<<<(B1N_ELEMS + B2N_ELEMS) / 256, 256, 0, stream>>>(W1, W2, B1, B2);

    const int E = in_sizes[1];                 // 800000
    const int nblocks = (E + BEDGES - 1) / BEDGES;   // 3125

    if (use_hb) {
        pack_h<<<(HN8 + 255) / 256, 256, 0, stream>>>(h, HB);
        edges_fused<true><<<nblocks, 512, 0, stream>>>(h, HB, src, dst, en, mu, B1, B2, (float*)d_out, E);
    } else {
        edges_fused<false><<<nblocks, 512, 0, stream>>>(h, nullptr, src, dst, en, mu, B1, B2, (float*)d_out, E);
    }
}